// Round 16
// baseline (57.777 us; speedup 1.0000x reference)
//
#include <hip/hip_runtime.h>
#include <hip/hip_bf16.h>
#include <math.h>

namespace {
constexpr int Bn = 4, Cin = 64, Cout = 64, Hh = 128, Ww = 128, Ho = 126, Wo = 126;
constexpr int HW = Hh * Ww;                 // 16384
constexpr int WOB = 63;                     // pixels per block (row-aligned)
constexpr int NBLK = Bn * Ho * 2;           // 1008 blocks (63 px each, exact)
constexpr int RSTR = 346;                   // region stride per cp: 5*68=340 + 6 pad
                                            // (RSTR % 8 == 2 -> conflict-free)
}

typedef __attribute__((ext_vector_type(8))) short bf16x8;
typedef __attribute__((ext_vector_type(4))) float f32x4;

__device__ __forceinline__ unsigned short f2bf(float f) {
    __hip_bfloat16 h = __float2bfloat16(f);
    return __builtin_bit_cast(unsigned short, h);
}
__device__ __forceinline__ float bf2f(unsigned short u) {
    unsigned int v = (unsigned int)u << 16;
    return __builtin_bit_cast(float, v);
}
__device__ __forceinline__ unsigned int f2bf_pk(float lo, float hi) {
    return (unsigned int)f2bf(lo) | ((unsigned int)f2bf(hi) << 16);
}
__device__ __forceinline__ bf16x8 mk8(unsigned int u0, unsigned int u1,
                                      unsigned int u2, unsigned int u3) {
    union { unsigned int u[4]; bf16x8 v; } x;
    x.u[0] = u0; x.u[1] = u1; x.u[2] = u2; x.u[3] = u3;
    return x.v;
}
// bijective XCD swizzle (m204): contiguous chunk of blocks per XCD
__device__ __forceinline__ int swz_block(int orig, int nwg) {
    int q = nwg >> 3, r = nwg & 7;
    int xcd = orig & 7, idx = orig >> 3;
    return (xcd < r ? xcd * (q + 1) : r * (q + 1) + (xcd - r) * q) + idx;
}

// ---------------------------------------------------------------------------
// prep + transpose merged (R13-proven, unchanged).
// ---------------------------------------------------------------------------
__global__ __launch_bounds__(256) void prep_transpose_kernel(
    const float* __restrict__ x, const float* __restrict__ w_off,
    const float* __restrict__ weight, unsigned int* __restrict__ xT16,
    unsigned short* __restrict__ wA_hi, unsigned short* __restrict__ wA_lo,
    unsigned short* __restrict__ wOff_hi, unsigned short* __restrict__ wOff_lo)
{
    int blk = blockIdx.x;
    if (blk < 1024) {
        __shared__ float t[64][65];
        int b    = blk >> 8;
        int hw0  = (blk & 255) * 64;
        int lane = (int)(threadIdx.x & 63);
        int w4   = (int)(threadIdx.x >> 6);

        const float* xb = x + b * (Cin * HW) + hw0;
#pragma unroll
        for (int i = 0; i < 16; ++i) {
            int cin = w4 * 16 + i;
            t[cin][lane] = xb[cin * HW + lane];
        }
        __syncthreads();
        unsigned int* dst = xT16 + ((size_t)b * HW + hw0) * 32;
        int px = (int)(threadIdx.x >> 2);
        int c8 = (int)(threadIdx.x & 3) * 8;
#pragma unroll
        for (int i = 0; i < 8; ++i) {
            int cp = c8 + i;
            dst[px * 32 + cp] = f2bf_pk(t[2 * cp][px], t[2 * cp + 1][px]);
        }
    } else {
        int i = (blk - 1024) * 256 + (int)threadIdx.x;
        if (i < 36864) {
            int j = i % 8;  int t = i / 8;
            int l = t % 64; t /= 64;
            int h = t % 2;  t /= 2;
            int w = t % 4;  int k = t / 4;
            int cout = 16 * w + (l & 15);
            int cin  = 32 * h + 8 * (l >> 4) + j;
            float v = weight[cout * 576 + cin * 9 + k];
            unsigned short hi = f2bf(v);
            wA_hi[i] = hi;
            wA_lo[i] = f2bf(v - bf2f(hi));

            int o = cout;
            float vo = o < 27 ? w_off[o * 576 + cin * 9 + k] : 0.f;
            unsigned short oh = f2bf(vo);
            wOff_hi[i] = oh;
            wOff_lo[i] = f2bf(vo - bf2f(oh));
        }
    }
}

// ---------------------------------------------------------------------------
// MERGED deformable conv, register-B edition. Block = 63 px of ONE row.
// Region[32 cp][5 rows][68 cols] staged once (conflict-free RSTR).
// Phase 0: offset conv direct-from-region (R15-proven) -> Ap[27][64].
// Phase 1: wave = px-tile. Each lane computes the 16 sampled cins of ITS
// MFMA B-fragment directly from region -> registers -> MFMA. No staging
// buffer, no phase-1 barriers. A-fragments looped over 4 cout-tiles.
// Scalar-uint LDS only (session rule).
// ---------------------------------------------------------------------------
__global__ __launch_bounds__(256, 3) void mdcn_kernel(
    const unsigned int* __restrict__ xT16, const float* __restrict__ b_off,
    const unsigned short* __restrict__ wOff_hi,
    const unsigned short* __restrict__ wOff_lo,
    const unsigned short* __restrict__ wA_hi,
    const unsigned short* __restrict__ wA_lo,
    const float* __restrict__ bias, float* __restrict__ out)
{
    __shared__ unsigned int region[32 * RSTR];   // 44.3 KB
    __shared__ float Ap[27][64];                 // 6.9 KB

    int wg   = swz_block(blockIdx.x, NBLK);
    int wid  = __builtin_amdgcn_readfirstlane((int)(threadIdx.x >> 6));
    int lane = (int)(threadIdx.x & 63);
    int b    = wg / 252;
    int rem  = wg - b * 252;
    int ho   = rem >> 1;
    int c0   = (rem & 1) * WOB;
    int x_lo = c0 - 1;

    const unsigned int* xTb = xT16 + (size_t)b * HW * 32;

    // ===================== region staging (once per block) ==================
    for (int i = 0; i < 11; ++i) {
        int idx4 = (int)threadIdx.x + 256 * i;
        if (idx4 < 2720) {
            int cp4 = (idx4 & 7) * 4;
            int rc  = idx4 >> 3;                 // row*68+col, 0..339
            int row = rc / 68;
            int col = rc - row * 68;
            int y = min(max(ho - 1 + row, 0), Hh - 1);
            int x = min(max(x_lo + col, 0), Ww - 1);
            uint4 q = *reinterpret_cast<const uint4*>(xTb + (y * Ww + x) * 32 + cp4);
            region[(cp4 + 0) * RSTR + rc] = q.x;
            region[(cp4 + 1) * RSTR + rc] = q.y;
            region[(cp4 + 2) * RSTR + rc] = q.z;
            region[(cp4 + 3) * RSTR + rc] = q.w;
        }
    }
    __syncthreads();

    // ======================= phase 0: offset conv (R15) ====================
    {
        int ct = wid & 1;
        int t0 = (wid >> 1) * 2;
        f32x4 acc0 = {0.f, 0.f, 0.f, 0.f}, acc1 = acc0;
        int g4 = (lane >> 4) * 4;

#pragma unroll
        for (int k = 0; k < 9; ++k) {
            int kh = k / 3, kw = k - 3 * kh;
            int roff = (kh + 1) * 68 + 1 + kw;
            const bf16x8* waH = reinterpret_cast<const bf16x8*>(
                wOff_hi + ((k * 4 + ct) * 2) * 512 + lane * 8);
            const bf16x8* waL = reinterpret_cast<const bf16x8*>(
                wOff_lo + ((k * 4 + ct) * 2) * 512 + lane * 8);
            bf16x8 a0h = waH[0], a1h = waH[64];
            bf16x8 a0l = waL[0], a1l = waL[64];
#pragma unroll
            for (int tt = 0; tt < 2; ++tt) {
                int px = 16 * (t0 + tt) + (lane & 15);
                int ci = roff + px;
                bf16x8 b0 = mk8(region[(g4 + 0) * RSTR + ci], region[(g4 + 1) * RSTR + ci],
                                region[(g4 + 2) * RSTR + ci], region[(g4 + 3) * RSTR + ci]);
                bf16x8 b1 = mk8(region[(16 + g4 + 0) * RSTR + ci], region[(16 + g4 + 1) * RSTR + ci],
                                region[(16 + g4 + 2) * RSTR + ci], region[(16 + g4 + 3) * RSTR + ci]);
                f32x4& a = tt ? acc1 : acc0;
                a = __builtin_amdgcn_mfma_f32_16x16x32_bf16(a0h, b0, a, 0, 0, 0);
                a = __builtin_amdgcn_mfma_f32_16x16x32_bf16(a0l, b0, a, 0, 0, 0);
                a = __builtin_amdgcn_mfma_f32_16x16x32_bf16(a1h, b1, a, 0, 0, 0);
                a = __builtin_amdgcn_mfma_f32_16x16x32_bf16(a1l, b1, a, 0, 0, 0);
            }
        }

#pragma unroll
        for (int tt = 0; tt < 2; ++tt) {
            f32x4 a = tt ? acc1 : acc0;
            int px = 16 * (t0 + tt) + (lane & 15);
#pragma unroll
            for (int rg = 0; rg < 4; ++rg) {
                int o = 16 * ct + 4 * (lane >> 4) + rg;
                if (o < 27) Ap[o][px] = a[rg];
            }
        }
        __syncthreads();
    }

    // =============== phase 1: sample + main conv, register-B ===============
    int g  = lane >> 4;           // cin group (fragment half index)
    int g4 = g * 4;               // cp base
    int pl = 16 * wid + (lane & 15);   // this lane's fragment pixel
    int pls = min(pl, 62);
    int wol = c0 + pls;

    f32x4 acc[4];
#pragma unroll
    for (int ct = 0; ct < 4; ++ct) acc[ct] = {0.f, 0.f, 0.f, 0.f};

#pragma unroll
    for (int k = 0; k < 9; ++k) {
        // --- params for pixel pl (broadcast Ap reads) ---
        float oy = Ap[2 * k][pl];
        float ox = Ap[2 * k + 1][pl];
        float mv = Ap[18 + k][pl] + b_off[18 + k];
        float ys = (float)(ho + k / 3) + oy + b_off[2 * k];
        float xs = (float)(wol + k % 3) + ox + b_off[2 * k + 1];
        float m  = 1.0f / (1.0f + expf(-mv));
        float y0f = floorf(ys), x0f = floorf(xs);
        float wy = ys - y0f, wx = xs - x0f;
        int y0 = (int)y0f, x0 = (int)x0f;
        float vy0 = (y0 >= 0  && y0 < Hh)     ? 1.f : 0.f;
        float vy1 = (y0 >= -1 && y0 < Hh - 1) ? 1.f : 0.f;
        float vx0 = (x0 >= 0  && x0 < Ww)     ? 1.f : 0.f;
        float vx1 = (x0 >= -1 && x0 < Ww - 1) ? 1.f : 0.f;
        float W00 = (1.f - wy) * (1.f - wx) * m * vy0 * vx0;
        float W01 = (1.f - wy) * wx         * m * vy0 * vx1;
        float W10 = wy         * (1.f - wx) * m * vy1 * vx0;
        float W11 = wy         * wx         * m * vy1 * vx1;

        // --- corner reads for THIS lane's cins: cp 4g..4g+3 and 16+4g..+3 ---
        unsigned int cu00[8], cu01[8], cu10[8], cu11[8];
        bool ok = (y0 >= ho - 1) && (y0 <= ho + 2) &&
                  (x0 >= x_lo) && (x0 <= x_lo + 66);
        if (ok) {
            int s00 = (y0 - (ho - 1)) * 68 + (x0 - x_lo);
#pragma unroll
            for (int j = 0; j < 4; ++j) {
                int basej = (g4 + j) * RSTR + s00;
                cu00[j] = region[basej];
                cu01[j] = region[basej + 1];
                cu10[j] = region[basej + 68];
                cu11[j] = region[basej + 69];
            }
#pragma unroll
            for (int j = 0; j < 4; ++j) {
                int basej = (16 + g4 + j) * RSTR + s00;
                cu00[4 + j] = region[basej];
                cu01[4 + j] = region[basej + 1];
                cu10[4 + j] = region[basej + 68];
                cu11[4 + j] = region[basej + 69];
            }
        } else {
            // global fallback; essentially never taken
            int y0c = min(max(y0, 0), Hh - 1), y1c = min(max(y0 + 1, 0), Hh - 1);
            int x0c = min(max(x0, 0), Ww - 1), x1c = min(max(x0 + 1, 0), Ww - 1);
            uint4 qa, qb;
            qa = *reinterpret_cast<const uint4*>(xTb + (y0c * Ww + x0c) * 32 + g4);
            qb = *reinterpret_cast<const uint4*>(xTb + (y0c * Ww + x0c) * 32 + 16 + g4);
            cu00[0]=qa.x; cu00[1]=qa.y; cu00[2]=qa.z; cu00[3]=qa.w;
            cu00[4]=qb.x; cu00[5]=qb.y; cu00[6]=qb.z; cu00[7]=qb.w;
            qa = *reinterpret_cast<const uint4*>(xTb + (y0c * Ww + x1c) * 32 + g4);
            qb = *reinterpret_cast<const uint4*>(xTb + (y0c * Ww + x1c) * 32 + 16 + g4);
            cu01[0]=qa.x; cu01[1]=qa.y; cu01[2]=qa.z; cu01[3]=qa.w;
            cu01[4]=qb.x; cu01[5]=qb.y; cu01[6]=qb.z; cu01[7]=qb.w;
            qa = *reinterpret_cast<const uint4*>(xTb + (y1c * Ww + x0c) * 32 + g4);
            qb = *reinterpret_cast<const uint4*>(xTb + (y1c * Ww + x0c) * 32 + 16 + g4);
            cu10[0]=qa.x; cu10[1]=qa.y; cu10[2]=qa.z; cu10[3]=qa.w;
            cu10[4]=qb.x; cu10[5]=qb.y; cu10[6]=qb.z; cu10[7]=qb.w;
            qa = *reinterpret_cast<const uint4*>(xTb + (y1c * Ww + x1c) * 32 + g4);
            qb = *reinterpret_cast<const uint4*>(xTb + (y1c * Ww + x1c) * 32 + 16 + g4);
            cu11[0]=qa.x; cu11[1]=qa.y; cu11[2]=qa.z; cu11[3]=qa.w;
            cu11[4]=qb.x; cu11[5]=qb.y; cu11[6]=qb.z; cu11[7]=qb.w;
        }

        // --- bilinear + pack -> B fragments in registers ---
        unsigned int pb[8];
#pragma unroll
        for (int j = 0; j < 8; ++j) {
            float c00a = bf2f((unsigned short)(cu00[j] & 0xffff));
            float c00b = bf2f((unsigned short)(cu00[j] >> 16));
            float c01a = bf2f((unsigned short)(cu01[j] & 0xffff));
            float c01b = bf2f((unsigned short)(cu01[j] >> 16));
            float c10a = bf2f((unsigned short)(cu10[j] & 0xffff));
            float c10b = bf2f((unsigned short)(cu10[j] >> 16));
            float c11a = bf2f((unsigned short)(cu11[j] & 0xffff));
            float c11b = bf2f((unsigned short)(cu11[j] >> 16));
            float s0 = W00 * c00a + W01 * c01a;
            s0 = fmaf(W10, c10a, s0); s0 = fmaf(W11, c11a, s0);
            float s1 = W00 * c00b + W01 * c01b;
            s1 = fmaf(W10, c10b, s1); s1 = fmaf(W11, c11b, s1);
            pb[j] = f2bf_pk(s0, s1);
        }
        bf16x8 b0 = mk8(pb[0], pb[1], pb[2], pb[3]);
        bf16x8 b1 = mk8(pb[4], pb[5], pb[6], pb[7]);

        // --- A-fragments per cout-tile + MFMA (proven formulas, ct for wid) ---
#pragma unroll
        for (int ct = 0; ct < 4; ++ct) {
            const bf16x8* waH = reinterpret_cast<const bf16x8*>(
                wA_hi + ((k * 4 + ct) * 2) * 512 + lane * 8);
            const bf16x8* waL = reinterpret_cast<const bf16x8*>(
                wA_lo + ((k * 4 + ct) * 2) * 512 + lane * 8);
            bf16x8 a0h = waH[0], a1h = waH[64];
            bf16x8 a0l = waL[0], a1l = waL[64];
            acc[ct] = __builtin_amdgcn_mfma_f32_16x16x32_bf16(a0h, b0, acc[ct], 0, 0, 0);
            acc[ct] = __builtin_amdgcn_mfma_f32_16x16x32_bf16(a0l, b0, acc[ct], 0, 0, 0);
            acc[ct] = __builtin_amdgcn_mfma_f32_16x16x32_bf16(a1h, b1, acc[ct], 0, 0, 0);
            acc[ct] = __builtin_amdgcn_mfma_f32_16x16x32_bf16(a1l, b1, acc[ct], 0, 0, 0);
        }
    }

    // ============================ epilogue =================================
    int ps = 16 * wid + (lane & 15);
    if (ps < WOB) {
        int col = c0 + ps;
#pragma unroll
        for (int ct = 0; ct < 4; ++ct) {
#pragma unroll
            for (int rg = 0; rg < 4; ++rg) {
                int cout = 16 * ct + 4 * (lane >> 4) + rg;
                float v = acc[ct][rg] + bias[cout];
                out[((b * Cout + cout) * Ho + ho) * Wo + col] = fmaxf(v, 0.f);
            }
        }
    }
}

extern "C" void kernel_launch(void* const* d_in, const int* in_sizes, int n_in,
                              void* d_out, int out_size, void* d_ws, size_t ws_size,
                              hipStream_t stream)
{
    const float* x      = (const float*)d_in[0];
    const float* w_off  = (const float*)d_in[1];
    const float* b_off  = (const float*)d_in[2];
    const float* weight = (const float*)d_in[3];
    const float* bias   = (const float*)d_in[4];

    unsigned int* xT16 = (unsigned int*)d_ws;                   // Bn*HW*32 uints
    unsigned short* wA_hi   = (unsigned short*)(xT16 + (size_t)Bn * HW * 32);
    unsigned short* wA_lo   = wA_hi + 36864;
    unsigned short* wOff_hi = wA_lo + 36864;
    unsigned short* wOff_lo = wOff_hi + 36864;

    prep_transpose_kernel<<<1024 + 144, 256, 0, stream>>>(
        x, w_off, weight, xT16, wA_hi, wA_lo, wOff_hi, wOff_lo);
    mdcn_kernel<<<NBLK, 256, 0, stream>>>(xT16, b_off, wOff_hi, wOff_lo,
                                          wA_hi, wA_lo, bias, (float*)d_out);
}

// Round 17
// 49.899 us; speedup vs baseline: 1.1579x; 1.1579x over previous
//
#include <hip/hip_runtime.h>
#include <hip/hip_bf16.h>
#include <math.h>

namespace {
constexpr int Bn = 4, Cin = 64, Cout = 64, Hh = 128, Ww = 128, Ho = 126, Wo = 126;
constexpr int HW = Hh * Ww;                 // 16384
constexpr int WOB = 63;                     // pixels per block (row-aligned)
constexpr int NBLK = Bn * Ho * 2;           // 1008 blocks (63 px each, exact)
constexpr int ROWU = 68;                    // staging row stride (uints): 64+4 pad
constexpr int RSTR = 346;                   // region stride per cp: 5*68=340 + 6 pad
                                            // (RSTR % 8 == 2 -> conflict-free)
}

typedef __attribute__((ext_vector_type(8))) short bf16x8;
typedef __attribute__((ext_vector_type(4))) float f32x4;

__device__ __forceinline__ unsigned short f2bf(float f) {
    __hip_bfloat16 h = __float2bfloat16(f);
    return __builtin_bit_cast(unsigned short, h);
}
__device__ __forceinline__ float bf2f(unsigned short u) {
    unsigned int v = (unsigned int)u << 16;
    return __builtin_bit_cast(float, v);
}
__device__ __forceinline__ unsigned int f2bf_pk(float lo, float hi) {
    return (unsigned int)f2bf(lo) | ((unsigned int)f2bf(hi) << 16);
}
__device__ __forceinline__ bf16x8 mk8(unsigned int u0, unsigned int u1,
                                      unsigned int u2, unsigned int u3) {
    union { unsigned int u[4]; bf16x8 v; } x;
    x.u[0] = u0; x.u[1] = u1; x.u[2] = u2; x.u[3] = u3;
    return x.v;
}
// bijective XCD swizzle (m204): contiguous chunk of blocks per XCD
__device__ __forceinline__ int swz_block(int orig, int nwg) {
    int q = nwg >> 3, r = nwg & 7;
    int xcd = orig & 7, idx = orig >> 3;
    return (xcd < r ? xcd * (q + 1) : r * (q + 1) + (xcd - r) * q) + idx;
}

// ---------------------------------------------------------------------------
// prep + transpose merged (R13-proven). Weights now plain bf16 (hi only).
// ---------------------------------------------------------------------------
__global__ __launch_bounds__(256) void prep_transpose_kernel(
    const float* __restrict__ x, const float* __restrict__ w_off,
    const float* __restrict__ weight, unsigned int* __restrict__ xT16,
    unsigned short* __restrict__ wA_hi, unsigned short* __restrict__ wOff_hi)
{
    int blk = blockIdx.x;
    if (blk < 1024) {
        __shared__ float t[64][65];
        int b    = blk >> 8;
        int hw0  = (blk & 255) * 64;
        int lane = (int)(threadIdx.x & 63);
        int w4   = (int)(threadIdx.x >> 6);

        const float* xb = x + b * (Cin * HW) + hw0;
#pragma unroll
        for (int i = 0; i < 16; ++i) {
            int cin = w4 * 16 + i;
            t[cin][lane] = xb[cin * HW + lane];
        }
        __syncthreads();
        unsigned int* dst = xT16 + ((size_t)b * HW + hw0) * 32;
        int px = (int)(threadIdx.x >> 2);
        int c8 = (int)(threadIdx.x & 3) * 8;
#pragma unroll
        for (int i = 0; i < 8; ++i) {
            int cp = c8 + i;
            dst[px * 32 + cp] = f2bf_pk(t[2 * cp][px], t[2 * cp + 1][px]);
        }
    } else {
        int i = (blk - 1024) * 256 + (int)threadIdx.x;
        if (i < 36864) {
            int j = i % 8;  int t = i / 8;
            int l = t % 64; t /= 64;
            int h = t % 2;  t /= 2;
            int w = t % 4;  int k = t / 4;
            int cout = 16 * w + (l & 15);
            int cin  = 32 * h + 8 * (l >> 4) + j;
            wA_hi[i] = f2bf(weight[cout * 576 + cin * 9 + k]);

            int o = cout;
            wOff_hi[i] = f2bf(o < 27 ? w_off[o * 576 + cin * 9 + k] : 0.f);
        }
    }
}

// ---------------------------------------------------------------------------
// MERGED deformable conv (R15 structure verbatim, lo-weight terms removed).
// Block = 63 px of ONE row. Region[32 cp][5 rows][68 cols] staged once.
// Phase 0: offset conv direct-from-region -> Ap[27][64].
// Phase 1: sample (corner reads from region) -> staging -> MFMA.
// Scalar-uint LDS only (session rule).
// ---------------------------------------------------------------------------
__global__ __launch_bounds__(256, 2) void mdcn_kernel(
    const unsigned int* __restrict__ xT16, const float* __restrict__ b_off,
    const unsigned short* __restrict__ wOff_hi,
    const unsigned short* __restrict__ wA_hi,
    const float* __restrict__ bias, float* __restrict__ out)
{
    __shared__ unsigned int region[32 * RSTR];   // 44.3 KB
    __shared__ unsigned int lds[2][32 * ROWU];   // 17.4 KB staging (dbuf)
    __shared__ float Ap[27][64];                 // 6.9 KB

    int wg   = swz_block(blockIdx.x, NBLK);
    int wid  = __builtin_amdgcn_readfirstlane((int)(threadIdx.x >> 6));
    int lane = (int)(threadIdx.x & 63);
    int b    = wg / 252;
    int rem  = wg - b * 252;
    int ho   = rem >> 1;
    int c0   = (rem & 1) * WOB;
    int x_lo = c0 - 1;
    int pxs  = min(lane, 62);
    int wo   = c0 + pxs;

    const unsigned int* xTb = xT16 + (size_t)b * HW * 32;

    // ===================== region staging (once per block) ==================
    for (int i = 0; i < 11; ++i) {
        int idx4 = (int)threadIdx.x + 256 * i;
        if (idx4 < 2720) {
            int cp4 = (idx4 & 7) * 4;
            int rc  = idx4 >> 3;                 // row*68+col, 0..339
            int row = rc / 68;
            int col = rc - row * 68;
            int y = min(max(ho - 1 + row, 0), Hh - 1);
            int x = min(max(x_lo + col, 0), Ww - 1);
            uint4 q = *reinterpret_cast<const uint4*>(xTb + (y * Ww + x) * 32 + cp4);
            region[(cp4 + 0) * RSTR + rc] = q.x;
            region[(cp4 + 1) * RSTR + rc] = q.y;
            region[(cp4 + 2) * RSTR + rc] = q.z;
            region[(cp4 + 3) * RSTR + rc] = q.w;
        }
    }
    __syncthreads();

    // ======================= phase 0: offset conv ==========================
    {
        int ct = wid & 1;
        int t0 = (wid >> 1) * 2;
        f32x4 acc0 = {0.f, 0.f, 0.f, 0.f}, acc1 = acc0;
        int g4 = (lane >> 4) * 4;

#pragma unroll
        for (int k = 0; k < 9; ++k) {
            int kh = k / 3, kw = k - 3 * kh;
            int roff = (kh + 1) * 68 + 1 + kw;
            const bf16x8* waH = reinterpret_cast<const bf16x8*>(
                wOff_hi + ((k * 4 + ct) * 2) * 512 + lane * 8);
            bf16x8 a0h = waH[0], a1h = waH[64];
#pragma unroll
            for (int tt = 0; tt < 2; ++tt) {
                int px = 16 * (t0 + tt) + (lane & 15);
                int ci = roff + px;
                bf16x8 b0 = mk8(region[(g4 + 0) * RSTR + ci], region[(g4 + 1) * RSTR + ci],
                                region[(g4 + 2) * RSTR + ci], region[(g4 + 3) * RSTR + ci]);
                bf16x8 b1 = mk8(region[(16 + g4 + 0) * RSTR + ci], region[(16 + g4 + 1) * RSTR + ci],
                                region[(16 + g4 + 2) * RSTR + ci], region[(16 + g4 + 3) * RSTR + ci]);
                f32x4& a = tt ? acc1 : acc0;
                a = __builtin_amdgcn_mfma_f32_16x16x32_bf16(a0h, b0, a, 0, 0, 0);
                a = __builtin_amdgcn_mfma_f32_16x16x32_bf16(a1h, b1, a, 0, 0, 0);
            }
        }

#pragma unroll
        for (int tt = 0; tt < 2; ++tt) {
            f32x4 a = tt ? acc1 : acc0;
            int px = 16 * (t0 + tt) + (lane & 15);
#pragma unroll
            for (int rg = 0; rg < 4; ++rg) {
                int o = 16 * ct + 4 * (lane >> 4) + rg;
                if (o < 27) Ap[o][px] = a[rg];
            }
        }
        __syncthreads();
    }

    // ======================= phase 1: sample + main conv ===================
    auto SAMPLE = [&](int k, int buf) {
        float oy = Ap[2 * k][lane];
        float ox = Ap[2 * k + 1][lane];
        float mv = Ap[18 + k][lane] + b_off[18 + k];
        float ys = (float)(ho + k / 3) + oy + b_off[2 * k];
        float xs = (float)(wo + k % 3) + ox + b_off[2 * k + 1];
        float m  = 1.0f / (1.0f + expf(-mv));
        float y0f = floorf(ys), x0f = floorf(xs);
        float wy = ys - y0f, wx = xs - x0f;
        int y0 = (int)y0f, x0 = (int)x0f;
        float vy0 = (y0 >= 0  && y0 < Hh)     ? 1.f : 0.f;
        float vy1 = (y0 >= -1 && y0 < Hh - 1) ? 1.f : 0.f;
        float vx0 = (x0 >= 0  && x0 < Ww)     ? 1.f : 0.f;
        float vx1 = (x0 >= -1 && x0 < Ww - 1) ? 1.f : 0.f;
        float W00 = (1.f - wy) * (1.f - wx) * m * vy0 * vx0;
        float W01 = (1.f - wy) * wx         * m * vy0 * vx1;
        float W10 = wy         * (1.f - wx) * m * vy1 * vx0;
        float W11 = wy         * wx         * m * vy1 * vx1;

        unsigned int cu00[8], cu01[8], cu10[8], cu11[8];
        bool ok = (y0 >= ho - 1) && (y0 <= ho + 2) &&
                  (x0 >= x_lo) && (x0 <= x_lo + 66);
        if (ok) {
            int s00 = (y0 - (ho - 1)) * 68 + (x0 - x_lo);
#pragma unroll
            for (int j = 0; j < 8; ++j) {
                int basej = (wid * 8 + j) * RSTR + s00;
                cu00[j] = region[basej];
                cu01[j] = region[basej + 1];
                cu10[j] = region[basej + 68];
                cu11[j] = region[basej + 69];
            }
        } else {
            // global fallback (exact); essentially never taken
            int y0c = min(max(y0, 0), Hh - 1), y1c = min(max(y0 + 1, 0), Hh - 1);
            int x0c = min(max(x0, 0), Ww - 1), x1c = min(max(x0 + 1, 0), Ww - 1);
            const unsigned int* bw = xTb + wid * 8;
            uint4 qa, qb;
            qa = *reinterpret_cast<const uint4*>(bw + (y0c * Ww + x0c) * 32);
            qb = *reinterpret_cast<const uint4*>(bw + (y0c * Ww + x0c) * 32 + 4);
            cu00[0]=qa.x; cu00[1]=qa.y; cu00[2]=qa.z; cu00[3]=qa.w;
            cu00[4]=qb.x; cu00[5]=qb.y; cu00[6]=qb.z; cu00[7]=qb.w;
            qa = *reinterpret_cast<const uint4*>(bw + (y0c * Ww + x1c) * 32);
            qb = *reinterpret_cast<const uint4*>(bw + (y0c * Ww + x1c) * 32 + 4);
            cu01[0]=qa.x; cu01[1]=qa.y; cu01[2]=qa.z; cu01[3]=qa.w;
            cu01[4]=qb.x; cu01[5]=qb.y; cu01[6]=qb.z; cu01[7]=qb.w;
            qa = *reinterpret_cast<const uint4*>(bw + (y1c * Ww + x0c) * 32);
            qb = *reinterpret_cast<const uint4*>(bw + (y1c * Ww + x0c) * 32 + 4);
            cu10[0]=qa.x; cu10[1]=qa.y; cu10[2]=qa.z; cu10[3]=qa.w;
            cu10[4]=qb.x; cu10[5]=qb.y; cu10[6]=qb.z; cu10[7]=qb.w;
            qa = *reinterpret_cast<const uint4*>(bw + (y1c * Ww + x1c) * 32);
            qb = *reinterpret_cast<const uint4*>(bw + (y1c * Ww + x1c) * 32 + 4);
            cu11[0]=qa.x; cu11[1]=qa.y; cu11[2]=qa.z; cu11[3]=qa.w;
            cu11[4]=qb.x; cu11[5]=qb.y; cu11[6]=qb.z; cu11[7]=qb.w;
        }

        unsigned int* dst = &lds[buf][(8 * wid) * ROWU + lane];
#pragma unroll
        for (int j = 0; j < 8; ++j) {
            float c00a = bf2f((unsigned short)(cu00[j] & 0xffff));
            float c00b = bf2f((unsigned short)(cu00[j] >> 16));
            float c01a = bf2f((unsigned short)(cu01[j] & 0xffff));
            float c01b = bf2f((unsigned short)(cu01[j] >> 16));
            float c10a = bf2f((unsigned short)(cu10[j] & 0xffff));
            float c10b = bf2f((unsigned short)(cu10[j] >> 16));
            float c11a = bf2f((unsigned short)(cu11[j] & 0xffff));
            float c11b = bf2f((unsigned short)(cu11[j] >> 16));
            float s0 = W00 * c00a + W01 * c01a;
            s0 = fmaf(W10, c10a, s0); s0 = fmaf(W11, c11a, s0);
            float s1 = W00 * c00b + W01 * c01b;
            s1 = fmaf(W10, c10b, s1); s1 = fmaf(W11, c11b, s1);
            dst[j * ROWU] = f2bf_pk(s0, s1);
        }
    };

    f32x4 acc[4];
#pragma unroll
    for (int t = 0; t < 4; ++t) acc[t] = {0.f, 0.f, 0.f, 0.f};

    SAMPLE(0, 0);
    __syncthreads();

#pragma unroll
    for (int k = 0; k < 9; ++k) {
        int cur = k & 1;
        if (k < 8) SAMPLE(k + 1, cur ^ 1);
        {
            const bf16x8* waH = reinterpret_cast<const bf16x8*>(
                wA_hi + ((k * 4 + wid) * 2) * 512 + lane * 8);
            bf16x8 a0h = waH[0], a1h = waH[64];
            const unsigned int* Lh = &lds[cur][0];
            int g4 = (lane >> 4) * 4;
#pragma unroll
            for (int t = 0; t < 4; ++t) {
                int colp = 16 * t + (lane & 15);
                bf16x8 b0 = mk8(Lh[(g4 + 0) * ROWU + colp], Lh[(g4 + 1) * ROWU + colp],
                                Lh[(g4 + 2) * ROWU + colp], Lh[(g4 + 3) * ROWU + colp]);
                bf16x8 b1 = mk8(Lh[(16 + g4 + 0) * ROWU + colp], Lh[(16 + g4 + 1) * ROWU + colp],
                                Lh[(16 + g4 + 2) * ROWU + colp], Lh[(16 + g4 + 3) * ROWU + colp]);
                acc[t] = __builtin_amdgcn_mfma_f32_16x16x32_bf16(a0h, b0, acc[t], 0, 0, 0);
                acc[t] = __builtin_amdgcn_mfma_f32_16x16x32_bf16(a1h, b1, acc[t], 0, 0, 0);
            }
        }
        __syncthreads();
    }

#pragma unroll
    for (int t = 0; t < 4; ++t) {
        int ps = 16 * t + (lane & 15);
        if (ps >= WOB) continue;             // skip pad slot 63
        int col = c0 + ps;
#pragma unroll
        for (int rg = 0; rg < 4; ++rg) {
            int cout = 16 * wid + 4 * (lane >> 4) + rg;
            float v = acc[t][rg] + bias[cout];
            out[((b * Cout + cout) * Ho + ho) * Wo + col] = fmaxf(v, 0.f);
        }
    }
}

extern "C" void kernel_launch(void* const* d_in, const int* in_sizes, int n_in,
                              void* d_out, int out_size, void* d_ws, size_t ws_size,
                              hipStream_t stream)
{
    const float* x      = (const float*)d_in[0];
    const float* w_off  = (const float*)d_in[1];
    const float* b_off  = (const float*)d_in[2];
    const float* weight = (const float*)d_in[3];
    const float* bias   = (const float*)d_in[4];

    unsigned int* xT16 = (unsigned int*)d_ws;                   // Bn*HW*32 uints
    unsigned short* wA_hi   = (unsigned short*)(xT16 + (size_t)Bn * HW * 32);
    unsigned short* wOff_hi = wA_hi + 36864;

    prep_transpose_kernel<<<1024 + 144, 256, 0, stream>>>(
        x, w_off, weight, xT16, wA_hi, wOff_hi);
    mdcn_kernel<<<NBLK, 256, 0, stream>>>(xT16, b_off, wOff_hi,
                                          wA_hi, bias, (float*)d_out);
}

// Round 18
// 48.621 us; speedup vs baseline: 1.1883x; 1.0263x over previous
//
#include <hip/hip_runtime.h>
#include <hip/hip_bf16.h>
#include <math.h>

namespace {
constexpr int Bn = 4, Cin = 64, Cout = 64, Hh = 128, Ww = 128, Ho = 126, Wo = 126;
constexpr int HW = Hh * Ww;                 // 16384
constexpr int WOB = 63;                     // pixels per block (row-aligned)
constexpr int NBLK = Bn * Ho * 2;           // 1008 blocks (63 px each, exact)
constexpr int RSTR = 346;                   // region stride per cp: 5*68=340 + 6 pad
                                            // (RSTR % 8 == 2 -> conflict-free)
}

typedef __attribute__((ext_vector_type(8))) short bf16x8;
typedef __attribute__((ext_vector_type(4))) float f32x4;

__device__ __forceinline__ unsigned short f2bf(float f) {
    __hip_bfloat16 h = __float2bfloat16(f);
    return __builtin_bit_cast(unsigned short, h);
}
__device__ __forceinline__ float bf2f(unsigned short u) {
    unsigned int v = (unsigned int)u << 16;
    return __builtin_bit_cast(float, v);
}
__device__ __forceinline__ unsigned int f2bf_pk(float lo, float hi) {
    return (unsigned int)f2bf(lo) | ((unsigned int)f2bf(hi) << 16);
}
__device__ __forceinline__ bf16x8 mk8(unsigned int u0, unsigned int u1,
                                      unsigned int u2, unsigned int u3) {
    union { unsigned int u[4]; bf16x8 v; } x;
    x.u[0] = u0; x.u[1] = u1; x.u[2] = u2; x.u[3] = u3;
    return x.v;
}
// bijective XCD swizzle (m204): contiguous chunk of blocks per XCD
__device__ __forceinline__ int swz_block(int orig, int nwg) {
    int q = nwg >> 3, r = nwg & 7;
    int xcd = orig & 7, idx = orig >> 3;
    return (xcd < r ? xcd * (q + 1) : r * (q + 1) + (xcd - r) * q) + idx;
}

// ---------------------------------------------------------------------------
// prep + transpose merged (R13-proven, R17-verbatim).
// ---------------------------------------------------------------------------
__global__ __launch_bounds__(256) void prep_transpose_kernel(
    const float* __restrict__ x, const float* __restrict__ w_off,
    const float* __restrict__ weight, unsigned int* __restrict__ xT16,
    unsigned short* __restrict__ wA_hi, unsigned short* __restrict__ wOff_hi)
{
    int blk = blockIdx.x;
    if (blk < 1024) {
        __shared__ float t[64][65];
        int b    = blk >> 8;
        int hw0  = (blk & 255) * 64;
        int lane = (int)(threadIdx.x & 63);
        int w4   = (int)(threadIdx.x >> 6);

        const float* xb = x + b * (Cin * HW) + hw0;
#pragma unroll
        for (int i = 0; i < 16; ++i) {
            int cin = w4 * 16 + i;
            t[cin][lane] = xb[cin * HW + lane];
        }
        __syncthreads();
        unsigned int* dst = xT16 + ((size_t)b * HW + hw0) * 32;
        int px = (int)(threadIdx.x >> 2);
        int c8 = (int)(threadIdx.x & 3) * 8;
#pragma unroll
        for (int i = 0; i < 8; ++i) {
            int cp = c8 + i;
            dst[px * 32 + cp] = f2bf_pk(t[2 * cp][px], t[2 * cp + 1][px]);
        }
    } else {
        int i = (blk - 1024) * 256 + (int)threadIdx.x;
        if (i < 36864) {
            int j = i % 8;  int t = i / 8;
            int l = t % 64; t /= 64;
            int h = t % 2;  t /= 2;
            int w = t % 4;  int k = t / 4;
            int cout = 16 * w + (l & 15);
            int cin  = 32 * h + 8 * (l >> 4) + j;
            wA_hi[i] = f2bf(weight[cout * 576 + cin * 9 + k]);

            int o = cout;
            wOff_hi[i] = f2bf(o < 27 ? w_off[o * 576 + cin * 9 + k] : 0.f);
        }
    }
}

// ---------------------------------------------------------------------------
// MERGED deformable conv (R17 structure; staging -> natively-typed uint4).
// Block = 63 px of ONE row. Region[32 cp][5 rows][68 cols] staged once.
// Phase 0: offset conv direct-from-region -> Ap[27][64] (R17-verbatim).
// Phase 1: corner reads scalar from region (R17-verbatim); staging is
// st4[buf][px][9] uint4 (row=36 uints): 2 b128 writes + 8 b128 frag reads
// per lane.k replace 8+32 scalars. NO reinterpret_cast on LDS anywhere.
// ---------------------------------------------------------------------------
__global__ __launch_bounds__(256, 2) void mdcn_kernel(
    const unsigned int* __restrict__ xT16, const float* __restrict__ b_off,
    const unsigned short* __restrict__ wOff_hi,
    const unsigned short* __restrict__ wA_hi,
    const float* __restrict__ bias, float* __restrict__ out)
{
    __shared__ unsigned int region[32 * RSTR];   // 44.3 KB
    __shared__ uint4 st4[2][64][9];              // 18.4 KB staging (dbuf)
    __shared__ float Ap[27][64];                 // 6.9 KB

    int wg   = swz_block(blockIdx.x, NBLK);
    int wid  = __builtin_amdgcn_readfirstlane((int)(threadIdx.x >> 6));
    int lane = (int)(threadIdx.x & 63);
    int b    = wg / 252;
    int rem  = wg - b * 252;
    int ho   = rem >> 1;
    int c0   = (rem & 1) * WOB;
    int x_lo = c0 - 1;
    int pxs  = min(lane, 62);
    int wo   = c0 + pxs;

    const unsigned int* xTb = xT16 + (size_t)b * HW * 32;

    // ===================== region staging (once per block) ==================
    for (int i = 0; i < 11; ++i) {
        int idx4 = (int)threadIdx.x + 256 * i;
        if (idx4 < 2720) {
            int cp4 = (idx4 & 7) * 4;
            int rc  = idx4 >> 3;                 // row*68+col, 0..339
            int row = rc / 68;
            int col = rc - row * 68;
            int y = min(max(ho - 1 + row, 0), Hh - 1);
            int x = min(max(x_lo + col, 0), Ww - 1);
            uint4 q = *reinterpret_cast<const uint4*>(xTb + (y * Ww + x) * 32 + cp4);
            region[(cp4 + 0) * RSTR + rc] = q.x;
            region[(cp4 + 1) * RSTR + rc] = q.y;
            region[(cp4 + 2) * RSTR + rc] = q.z;
            region[(cp4 + 3) * RSTR + rc] = q.w;
        }
    }
    __syncthreads();

    // ======================= phase 0: offset conv ==========================
    {
        int ct = wid & 1;
        int t0 = (wid >> 1) * 2;
        f32x4 acc0 = {0.f, 0.f, 0.f, 0.f}, acc1 = acc0;
        int g4 = (lane >> 4) * 4;

#pragma unroll
        for (int k = 0; k < 9; ++k) {
            int kh = k / 3, kw = k - 3 * kh;
            int roff = (kh + 1) * 68 + 1 + kw;
            const bf16x8* waH = reinterpret_cast<const bf16x8*>(
                wOff_hi + ((k * 4 + ct) * 2) * 512 + lane * 8);
            bf16x8 a0h = waH[0], a1h = waH[64];
#pragma unroll
            for (int tt = 0; tt < 2; ++tt) {
                int px = 16 * (t0 + tt) + (lane & 15);
                int ci = roff + px;
                bf16x8 b0 = mk8(region[(g4 + 0) * RSTR + ci], region[(g4 + 1) * RSTR + ci],
                                region[(g4 + 2) * RSTR + ci], region[(g4 + 3) * RSTR + ci]);
                bf16x8 b1 = mk8(region[(16 + g4 + 0) * RSTR + ci], region[(16 + g4 + 1) * RSTR + ci],
                                region[(16 + g4 + 2) * RSTR + ci], region[(16 + g4 + 3) * RSTR + ci]);
                f32x4& a = tt ? acc1 : acc0;
                a = __builtin_amdgcn_mfma_f32_16x16x32_bf16(a0h, b0, a, 0, 0, 0);
                a = __builtin_amdgcn_mfma_f32_16x16x32_bf16(a1h, b1, a, 0, 0, 0);
            }
        }

#pragma unroll
        for (int tt = 0; tt < 2; ++tt) {
            f32x4 a = tt ? acc1 : acc0;
            int px = 16 * (t0 + tt) + (lane & 15);
#pragma unroll
            for (int rg = 0; rg < 4; ++rg) {
                int o = 16 * ct + 4 * (lane >> 4) + rg;
                if (o < 27) Ap[o][px] = a[rg];
            }
        }
        __syncthreads();
    }

    // ======================= phase 1: sample + main conv ===================
    auto SAMPLE = [&](int k, int buf) {
        float oy = Ap[2 * k][lane];
        float ox = Ap[2 * k + 1][lane];
        float mv = Ap[18 + k][lane] + b_off[18 + k];
        float ys = (float)(ho + k / 3) + oy + b_off[2 * k];
        float xs = (float)(wo + k % 3) + ox + b_off[2 * k + 1];
        float m  = 1.0f / (1.0f + expf(-mv));
        float y0f = floorf(ys), x0f = floorf(xs);
        float wy = ys - y0f, wx = xs - x0f;
        int y0 = (int)y0f, x0 = (int)x0f;
        float vy0 = (y0 >= 0  && y0 < Hh)     ? 1.f : 0.f;
        float vy1 = (y0 >= -1 && y0 < Hh - 1) ? 1.f : 0.f;
        float vx0 = (x0 >= 0  && x0 < Ww)     ? 1.f : 0.f;
        float vx1 = (x0 >= -1 && x0 < Ww - 1) ? 1.f : 0.f;
        float W00 = (1.f - wy) * (1.f - wx) * m * vy0 * vx0;
        float W01 = (1.f - wy) * wx         * m * vy0 * vx1;
        float W10 = wy         * (1.f - wx) * m * vy1 * vx0;
        float W11 = wy         * wx         * m * vy1 * vx1;

        unsigned int cu00[8], cu01[8], cu10[8], cu11[8];
        bool ok = (y0 >= ho - 1) && (y0 <= ho + 2) &&
                  (x0 >= x_lo) && (x0 <= x_lo + 66);
        if (ok) {
            int s00 = (y0 - (ho - 1)) * 68 + (x0 - x_lo);
#pragma unroll
            for (int j = 0; j < 8; ++j) {
                int basej = (wid * 8 + j) * RSTR + s00;
                cu00[j] = region[basej];
                cu01[j] = region[basej + 1];
                cu10[j] = region[basej + 68];
                cu11[j] = region[basej + 69];
            }
        } else {
            // global fallback (exact); essentially never taken
            int y0c = min(max(y0, 0), Hh - 1), y1c = min(max(y0 + 1, 0), Hh - 1);
            int x0c = min(max(x0, 0), Ww - 1), x1c = min(max(x0 + 1, 0), Ww - 1);
            const unsigned int* bw = xTb + wid * 8;
            uint4 qa, qb;
            qa = *reinterpret_cast<const uint4*>(bw + (y0c * Ww + x0c) * 32);
            qb = *reinterpret_cast<const uint4*>(bw + (y0c * Ww + x0c) * 32 + 4);
            cu00[0]=qa.x; cu00[1]=qa.y; cu00[2]=qa.z; cu00[3]=qa.w;
            cu00[4]=qb.x; cu00[5]=qb.y; cu00[6]=qb.z; cu00[7]=qb.w;
            qa = *reinterpret_cast<const uint4*>(bw + (y0c * Ww + x1c) * 32);
            qb = *reinterpret_cast<const uint4*>(bw + (y0c * Ww + x1c) * 32 + 4);
            cu01[0]=qa.x; cu01[1]=qa.y; cu01[2]=qa.z; cu01[3]=qa.w;
            cu01[4]=qb.x; cu01[5]=qb.y; cu01[6]=qb.z; cu01[7]=qb.w;
            qa = *reinterpret_cast<const uint4*>(bw + (y1c * Ww + x0c) * 32);
            qb = *reinterpret_cast<const uint4*>(bw + (y1c * Ww + x0c) * 32 + 4);
            cu10[0]=qa.x; cu10[1]=qa.y; cu10[2]=qa.z; cu10[3]=qa.w;
            cu10[4]=qb.x; cu10[5]=qb.y; cu10[6]=qb.z; cu10[7]=qb.w;
            qa = *reinterpret_cast<const uint4*>(bw + (y1c * Ww + x1c) * 32);
            qb = *reinterpret_cast<const uint4*>(bw + (y1c * Ww + x1c) * 32 + 4);
            cu11[0]=qa.x; cu11[1]=qa.y; cu11[2]=qa.z; cu11[3]=qa.w;
            cu11[4]=qb.x; cu11[5]=qb.y; cu11[6]=qb.z; cu11[7]=qb.w;
        }

        unsigned int pb[8];
#pragma unroll
        for (int j = 0; j < 8; ++j) {
            float c00a = bf2f((unsigned short)(cu00[j] & 0xffff));
            float c00b = bf2f((unsigned short)(cu00[j] >> 16));
            float c01a = bf2f((unsigned short)(cu01[j] & 0xffff));
            float c01b = bf2f((unsigned short)(cu01[j] >> 16));
            float c10a = bf2f((unsigned short)(cu10[j] & 0xffff));
            float c10b = bf2f((unsigned short)(cu10[j] >> 16));
            float c11a = bf2f((unsigned short)(cu11[j] & 0xffff));
            float c11b = bf2f((unsigned short)(cu11[j] >> 16));
            float s0 = W00 * c00a + W01 * c01a;
            s0 = fmaf(W10, c10a, s0); s0 = fmaf(W11, c11a, s0);
            float s1 = W00 * c00b + W01 * c01b;
            s1 = fmaf(W10, c10b, s1); s1 = fmaf(W11, c11b, s1);
            pb[j] = f2bf_pk(s0, s1);
        }
        st4[buf][lane][wid * 2]     = make_uint4(pb[0], pb[1], pb[2], pb[3]);
        st4[buf][lane][wid * 2 + 1] = make_uint4(pb[4], pb[5], pb[6], pb[7]);
    };

    f32x4 acc[4];
#pragma unroll
    for (int t = 0; t < 4; ++t) acc[t] = {0.f, 0.f, 0.f, 0.f};

    SAMPLE(0, 0);
    __syncthreads();

#pragma unroll
    for (int k = 0; k < 9; ++k) {
        int cur = k & 1;
        if (k < 8) SAMPLE(k + 1, cur ^ 1);
        {
            const bf16x8* waH = reinterpret_cast<const bf16x8*>(
                wA_hi + ((k * 4 + wid) * 2) * 512 + lane * 8);
            bf16x8 a0h = waH[0], a1h = waH[64];
            int g = lane >> 4;
#pragma unroll
            for (int t = 0; t < 4; ++t) {
                int px = 16 * t + (lane & 15);
                uint4 v0 = st4[cur][px][g];
                uint4 v1 = st4[cur][px][4 + g];
                bf16x8 b0 = mk8(v0.x, v0.y, v0.z, v0.w);
                bf16x8 b1 = mk8(v1.x, v1.y, v1.z, v1.w);
                acc[t] = __builtin_amdgcn_mfma_f32_16x16x32_bf16(a0h, b0, acc[t], 0, 0, 0);
                acc[t] = __builtin_amdgcn_mfma_f32_16x16x32_bf16(a1h, b1, acc[t], 0, 0, 0);
            }
        }
        __syncthreads();
    }

#pragma unroll
    for (int t = 0; t < 4; ++t) {
        int ps = 16 * t + (lane & 15);
        if (ps >= WOB) continue;             // skip pad slot 63
        int col = c0 + ps;
#pragma unroll
        for (int rg = 0; rg < 4; ++rg) {
            int cout = 16 * wid + 4 * (lane >> 4) + rg;
            float v = acc[t][rg] + bias[cout];
            out[((b * Cout + cout) * Ho + ho) * Wo + col] = fmaxf(v, 0.f);
        }
    }
}

extern "C" void kernel_launch(void* const* d_in, const int* in_sizes, int n_in,
                              void* d_out, int out_size, void* d_ws, size_t ws_size,
                              hipStream_t stream)
{
    const float* x      = (const float*)d_in[0];
    const float* w_off  = (const float*)d_in[1];
    const float* b_off  = (const float*)d_in[2];
    const float* weight = (const float*)d_in[3];
    const float* bias   = (const float*)d_in[4];

    unsigned int* xT16 = (unsigned int*)d_ws;                   // Bn*HW*32 uints
    unsigned short* wA_hi   = (unsigned short*)(xT16 + (size_t)Bn * HW * 32);
    unsigned short* wOff_hi = wA_hi + 36864;

    prep_transpose_kernel<<<1024 + 144, 256, 0, stream>>>(
        x, w_off, weight, xT16, wA_hi, wOff_hi);
    mdcn_kernel<<<NBLK, 256, 0, stream>>>(xT16, b_off, wOff_hi,
                                          wA_hi, bias, (float*)d_out);
}